// Round 1
// baseline (791.970 us; speedup 1.0000x reference)
//
#include <hip/hip_runtime.h>
#include <math.h>

#define NN 50000
#define NE 600000
#define DD 128

// ---------------- elementwise tanh ----------------
__global__ __launch_bounds__(256) void k_tanh(const float* __restrict__ x,
                                              float* __restrict__ y) {
  int i = blockIdx.x * 256 + threadIdx.x;
  if (i < NN * DD / 4) {
    float4 v = reinterpret_cast<const float4*>(x)[i];
    float4 r;
    r.x = tanhf(v.x); r.y = tanhf(v.y); r.z = tanhf(v.z); r.w = tanhf(v.w);
    reinterpret_cast<float4*>(y)[i] = r;
  }
}

// ---------------- degree count ----------------
__global__ __launch_bounds__(256) void k_deg(const int* __restrict__ src,
                                             const int* __restrict__ dst,
                                             int* __restrict__ co,
                                             int* __restrict__ ci) {
  int e = blockIdx.x * 256 + threadIdx.x;
  if (e < NE) {
    atomicAdd(&co[src[e]], 1);
    atomicAdd(&ci[dst[e]], 1);
  }
}

__global__ __launch_bounds__(256) void k_norm(const int* __restrict__ co,
                                              const int* __restrict__ ci,
                                              float* __restrict__ no,
                                              float* __restrict__ ni) {
  int i = blockIdx.x * 256 + threadIdx.x;
  if (i < NN) {
    no[i] = rsqrtf((float)max(co[i], 1));
    ni[i] = rsqrtf((float)max(ci[i], 1));
  }
}

// ---------------- exclusive scan of in-degrees (3 kernels) ----------------
__global__ __launch_bounds__(1024) void k_scanA(const int* __restrict__ deg,
                                                int* __restrict__ incl,
                                                int* __restrict__ bsum) {
  int tid = threadIdx.x;
  int gid = blockIdx.x * 1024 + tid;
  int v = (gid < NN) ? deg[gid] : 0;
  int lane = tid & 63;
  #pragma unroll
  for (int o = 1; o < 64; o <<= 1) {
    int n = __shfl_up(v, o);
    if (lane >= o) v += n;
  }
  __shared__ int ws[16];
  int wid = tid >> 6;
  if (lane == 63) ws[wid] = v;
  __syncthreads();
  if (tid < 16) {
    int s = ws[tid];
    #pragma unroll
    for (int o = 1; o < 16; o <<= 1) {
      int n = __shfl_up(s, o);
      if (tid >= o) s += n;
    }
    ws[tid] = s;
  }
  __syncthreads();
  if (wid > 0) v += ws[wid - 1];
  if (gid < NN) incl[gid] = v;
  if (tid == 1023) bsum[blockIdx.x] = v;
}

__global__ __launch_bounds__(64) void k_scanB(const int* __restrict__ bsum,
                                              int* __restrict__ boff, int nb) {
  int t = threadIdx.x;
  int v = (t < nb) ? bsum[t] : 0;
  int orig = v;
  #pragma unroll
  for (int o = 1; o < 64; o <<= 1) {
    int n = __shfl_up(v, o);
    if (t >= o) v += n;
  }
  if (t < nb) boff[t] = v - orig;  // exclusive
}

__global__ __launch_bounds__(256) void k_scanC(const int* __restrict__ incl,
                                               const int* __restrict__ deg,
                                               const int* __restrict__ boff,
                                               int* __restrict__ rp) {
  int i = blockIdx.x * 256 + threadIdx.x;
  if (i < NN) rp[i] = incl[i] - deg[i] + boff[i >> 10];
  if (i == 0) rp[NN] = NE;
}

// ---------------- CSR bucket fill ----------------
__global__ __launch_bounds__(256) void k_fill(const int* __restrict__ src,
                                              const int* __restrict__ dst,
                                              const int* __restrict__ rp,
                                              int* __restrict__ fill,
                                              int* __restrict__ colsrc) {
  int e = blockIdx.x * 256 + threadIdx.x;
  if (e < NE) {
    int d = dst[e];
    int pos = rp[d] + atomicAdd(&fill[d], 1);
    colsrc[pos] = src[e];
  }
}

// ---------------- APPNP fused iteration: out = 0.8*ni*sum(no[s]*h[s]) + 0.2*x0 ----
__global__ __launch_bounds__(256) void k_appnp(const float* __restrict__ h,
                                               const float* __restrict__ x0,
                                               const float* __restrict__ no,
                                               const float* __restrict__ ni,
                                               const int* __restrict__ rp,
                                               const int* __restrict__ cs,
                                               float* __restrict__ outp) {
  int w = (blockIdx.x * 256 + threadIdx.x) >> 6;  // node = wave
  int lane = threadIdx.x & 63;
  if (w >= NN) return;
  int beg = rp[w], end = rp[w + 1];
  float ax = 0.f, ay = 0.f;
  for (int j = beg; j < end; ++j) {
    int s = cs[j];
    float sc = no[s];
    float2 v = *reinterpret_cast<const float2*>(h + (size_t)s * DD + lane * 2);
    ax += sc * v.x;
    ay += sc * v.y;
  }
  float wi = 0.8f * ni[w];
  float2 xv = *reinterpret_cast<const float2*>(x0 + (size_t)w * DD + lane * 2);
  float2 r;
  r.x = wi * ax + 0.2f * xv.x;
  r.y = wi * ay + 0.2f * xv.y;
  *reinterpret_cast<float2*>(outp + (size_t)w * DD + lane * 2) = r;
}

// ---------------- plain neighbor sum: out = sum(h[s]) ----------------
__global__ __launch_bounds__(256) void k_gather(const float* __restrict__ h,
                                                const int* __restrict__ rp,
                                                const int* __restrict__ cs,
                                                float* __restrict__ outp) {
  int w = (blockIdx.x * 256 + threadIdx.x) >> 6;
  int lane = threadIdx.x & 63;
  if (w >= NN) return;
  int beg = rp[w], end = rp[w + 1];
  float ax = 0.f, ay = 0.f;
  for (int j = beg; j < end; ++j) {
    int s = cs[j];
    float2 v = *reinterpret_cast<const float2*>(h + (size_t)s * DD + lane * 2);
    ax += v.x;
    ay += v.y;
  }
  float2 r; r.x = ax; r.y = ay;
  *reinterpret_cast<float2*>(outp + (size_t)w * DD + lane * 2) = r;
}

// ---------------- GIN GEMM: out = ((1+eps)*p + a) @ W + b  (+ optional mish) ----
// z row = [ (1+eps)*p0 + a0 | (1+eps)*p1 + a1 ]  (second half only when KTOT==256)
template <int KTOT, bool MISH>
__global__ __launch_bounds__(256) void k_gemm(const float* __restrict__ p0,
                                              const float* __restrict__ a0,
                                              const float* __restrict__ p1,
                                              const float* __restrict__ a1,
                                              const float* __restrict__ Wg,
                                              const float* __restrict__ bias,
                                              const float* __restrict__ epsp,
                                              float* __restrict__ outp) {
  __shared__ float Al[64 * 33];
  __shared__ float Wl[32 * 128];
  const int tid = threadIdx.x;
  const int rowBase = blockIdx.x * 64;
  const float e1 = 1.0f + epsp[0];
  float acc[4][8];
  #pragma unroll
  for (int i = 0; i < 4; ++i)
    #pragma unroll
    for (int j = 0; j < 8; ++j) acc[i][j] = 0.f;
  const int ty = tid >> 4, tx = tid & 15;

  for (int kc = 0; kc < KTOT; kc += 32) {
    const float* P;
    const float* A;
    int kkb;
    if (KTOT == 256 && kc >= 128) { P = p1; A = a1; kkb = kc - 128; }
    else { P = p0; A = a0; kkb = kc; }
    // A tile: 64 rows x 32 k
    #pragma unroll
    for (int it = 0; it < 2; ++it) {
      int idx = tid + it * 256;       // [0,512)
      int r = idx >> 3, q = idx & 7;  // k_local = q*4
      int grow = rowBase + r;
      float4 z;
      if (grow < NN) {
        float4 vp = *reinterpret_cast<const float4*>(P + (size_t)grow * DD + kkb + q * 4);
        float4 va = *reinterpret_cast<const float4*>(A + (size_t)grow * DD + kkb + q * 4);
        z.x = e1 * vp.x + va.x;
        z.y = e1 * vp.y + va.y;
        z.z = e1 * vp.z + va.z;
        z.w = e1 * vp.w + va.w;
      } else {
        z.x = z.y = z.z = z.w = 0.f;
      }
      int b = r * 33 + q * 4;
      Al[b] = z.x; Al[b + 1] = z.y; Al[b + 2] = z.z; Al[b + 3] = z.w;
    }
    // W tile: 32 x 128, contiguous
    #pragma unroll
    for (int it = 0; it < 4; ++it) {
      int idx = tid + it * 256;  // [0,1024)
      float4 w = *reinterpret_cast<const float4*>(Wg + (size_t)kc * DD + idx * 4);
      *reinterpret_cast<float4*>(&Wl[idx * 4]) = w;
    }
    __syncthreads();
    #pragma unroll 4
    for (int k = 0; k < 32; ++k) {
      float av[4], wv[8];
      #pragma unroll
      for (int i = 0; i < 4; ++i) av[i] = Al[(ty + 16 * i) * 33 + k];
      #pragma unroll
      for (int j = 0; j < 8; ++j) wv[j] = Wl[k * DD + tx + 16 * j];
      #pragma unroll
      for (int i = 0; i < 4; ++i)
        #pragma unroll
        for (int j = 0; j < 8; ++j) acc[i][j] += av[i] * wv[j];
    }
    __syncthreads();
  }
  #pragma unroll
  for (int i = 0; i < 4; ++i) {
    int grow = rowBase + ty + 16 * i;
    if (grow < NN) {
      #pragma unroll
      for (int j = 0; j < 8; ++j) {
        int c = tx + 16 * j;
        float v = acc[i][j] + bias[c];
        if (MISH) {
          float sp = (v > 20.f) ? v : log1pf(expf(v));
          v = v * tanhf(sp);
        }
        outp[(size_t)grow * DD + c] = v;
      }
    }
  }
}

extern "C" void kernel_launch(void* const* d_in, const int* in_sizes, int n_in,
                              void* d_out, int out_size, void* d_ws, size_t ws_size,
                              hipStream_t stream) {
  const float* x = (const float*)d_in[0];
  const int* src = (const int*)d_in[1];
  const int* dst = (const int*)d_in[2];
  const float* W1 = (const float*)d_in[3];
  const float* b1 = (const float*)d_in[4];
  const float* W2 = (const float*)d_in[5];
  const float* b2 = (const float*)d_in[6];
  const float* eps1 = (const float*)d_in[7];
  const float* eps2 = (const float*)d_in[8];
  float* out = (float*)d_out;

  char* ws = (char*)d_ws;
  size_t off = 0;
  auto alloc = [&](size_t bytes) -> void* {
    void* p = ws + off;
    off += (bytes + 255) & ~(size_t)255;
    return p;
  };
  const size_t ND = (size_t)NN * DD;
  float* x0 = (float*)alloc(ND * 4);
  float* hA = (float*)alloc(ND * 4);
  float* hB = (float*)alloc(ND * 4);
  float* g1 = (float*)alloc(ND * 4);
  int* cnt_o = (int*)alloc(NN * 4);
  int* cnt_i = (int*)alloc(NN * 4);
  float* nrm_o = (float*)alloc(NN * 4);
  float* nrm_i = (float*)alloc(NN * 4);
  int* incl = (int*)alloc(NN * 4);
  int* bsum = (int*)alloc(64 * 4);
  int* boff = (int*)alloc(64 * 4);
  int* rp = (int*)alloc((NN + 1) * 4);
  int* fillc = (int*)alloc(NN * 4);
  int* colsrc = (int*)alloc(NE * 4);

  hipMemsetAsync(cnt_o, 0, NN * 4, stream);
  hipMemsetAsync(cnt_i, 0, NN * 4, stream);
  hipMemsetAsync(fillc, 0, NN * 4, stream);

  k_tanh<<<(NN * DD / 4 + 255) / 256, 256, 0, stream>>>(x, x0);

  const int EB = (NE + 255) / 256;
  k_deg<<<EB, 256, 0, stream>>>(src, dst, cnt_o, cnt_i);
  k_norm<<<(NN + 255) / 256, 256, 0, stream>>>(cnt_o, cnt_i, nrm_o, nrm_i);

  const int SB = (NN + 1023) / 1024;  // 49
  k_scanA<<<SB, 1024, 0, stream>>>(cnt_i, incl, bsum);
  k_scanB<<<1, 64, 0, stream>>>(bsum, boff, SB);
  k_scanC<<<(NN + 255) / 256, 256, 0, stream>>>(incl, cnt_i, boff, rp);
  k_fill<<<EB, 256, 0, stream>>>(src, dst, rp, fillc, colsrc);

  const int GB = (NN * 64 + 255) / 256;  // wave per node
  // APPNP x5: x0 -> hA -> hB -> hA -> hB -> hA
  k_appnp<<<GB, 256, 0, stream>>>(x0, x0, nrm_o, nrm_i, rp, colsrc, hA);
  k_appnp<<<GB, 256, 0, stream>>>(hA, x0, nrm_o, nrm_i, rp, colsrc, hB);
  k_appnp<<<GB, 256, 0, stream>>>(hB, x0, nrm_o, nrm_i, rp, colsrc, hA);
  k_appnp<<<GB, 256, 0, stream>>>(hA, x0, nrm_o, nrm_i, rp, colsrc, hB);
  k_appnp<<<GB, 256, 0, stream>>>(hB, x0, nrm_o, nrm_i, rp, colsrc, hA);

  // GIN1: agg(hA) -> hB ; g1 = ((1+eps1)*hA + hB) @ W1 + b1
  k_gather<<<GB, 256, 0, stream>>>(hA, rp, colsrc, hB);
  const int MB = (NN + 63) / 64;
  k_gemm<128, false><<<MB, 256, 0, stream>>>(hA, hB, nullptr, nullptr, W1, b1, eps1, g1);

  // GIN2: aggA(g1) -> hA ; aggB(x0) -> hB ;
  // out = mish([ (1+eps2)*g1 + hA | (1+eps2)*x0 + hB ] @ W2 + b2)
  k_gather<<<GB, 256, 0, stream>>>(g1, rp, colsrc, hA);
  k_gather<<<GB, 256, 0, stream>>>(x0, rp, colsrc, hB);
  k_gemm<256, true><<<MB, 256, 0, stream>>>(g1, hA, x0, hB, W2, b2, eps2, out);
}

// Round 2
// 544.128 us; speedup vs baseline: 1.4555x; 1.4555x over previous
//
#include <hip/hip_runtime.h>
#include <hip/hip_fp16.h>
#include <math.h>

#define NN 50000
#define NE 600000
#define DD 128

union F2H { float2 f; __half2 h[2]; };

// ---------------- tanh + dual fp16 write (plain and *norm_o) ----------------
__global__ __launch_bounds__(256) void k_tanh(const float* __restrict__ x,
                                              const float* __restrict__ no,
                                              __half2* __restrict__ x0h,
                                              __half2* __restrict__ x0n) {
  int i = blockIdx.x * 256 + threadIdx.x;
  if (i >= NN * DD / 4) return;
  float4 v = reinterpret_cast<const float4*>(x)[i];
  float t0 = tanhf(v.x), t1 = tanhf(v.y), t2 = tanhf(v.z), t3 = tanhf(v.w);
  float s = no[i >> 5];  // 32 float4 per node row
  F2H a, b;
  a.h[0] = __floats2half2_rn(t0, t1);
  a.h[1] = __floats2half2_rn(t2, t3);
  b.h[0] = __floats2half2_rn(t0 * s, t1 * s);
  b.h[1] = __floats2half2_rn(t2 * s, t3 * s);
  reinterpret_cast<float2*>(x0h)[i] = a.f;
  reinterpret_cast<float2*>(x0n)[i] = b.f;
}

// ---------------- degree count ----------------
__global__ __launch_bounds__(256) void k_deg(const int* __restrict__ src,
                                             const int* __restrict__ dst,
                                             int* __restrict__ co,
                                             int* __restrict__ ci) {
  int e = blockIdx.x * 256 + threadIdx.x;
  if (e < NE) {
    atomicAdd(&co[src[e]], 1);
    atomicAdd(&ci[dst[e]], 1);
  }
}

__global__ __launch_bounds__(256) void k_norm(const int* __restrict__ co,
                                              const int* __restrict__ ci,
                                              float* __restrict__ no,
                                              float* __restrict__ ni) {
  int i = blockIdx.x * 256 + threadIdx.x;
  if (i < NN) {
    no[i] = rsqrtf((float)max(co[i], 1));
    ni[i] = rsqrtf((float)max(ci[i], 1));
  }
}

// ---------------- exclusive scan of in-degrees ----------------
__global__ __launch_bounds__(1024) void k_scanA(const int* __restrict__ deg,
                                                int* __restrict__ incl,
                                                int* __restrict__ bsum) {
  int tid = threadIdx.x;
  int gid = blockIdx.x * 1024 + tid;
  int v = (gid < NN) ? deg[gid] : 0;
  int lane = tid & 63;
  #pragma unroll
  for (int o = 1; o < 64; o <<= 1) {
    int n = __shfl_up(v, o);
    if (lane >= o) v += n;
  }
  __shared__ int ws[16];
  int wid = tid >> 6;
  if (lane == 63) ws[wid] = v;
  __syncthreads();
  if (tid < 16) {
    int s = ws[tid];
    #pragma unroll
    for (int o = 1; o < 16; o <<= 1) {
      int n = __shfl_up(s, o);
      if (tid >= o) s += n;
    }
    ws[tid] = s;
  }
  __syncthreads();
  if (wid > 0) v += ws[wid - 1];
  if (gid < NN) incl[gid] = v;
  if (tid == 1023) bsum[blockIdx.x] = v;
}

__global__ __launch_bounds__(64) void k_scanB(const int* __restrict__ bsum,
                                              int* __restrict__ boff, int nb) {
  int t = threadIdx.x;
  int v = (t < nb) ? bsum[t] : 0;
  int orig = v;
  #pragma unroll
  for (int o = 1; o < 64; o <<= 1) {
    int n = __shfl_up(v, o);
    if (t >= o) v += n;
  }
  if (t < nb) boff[t] = v - orig;  // exclusive
}

__global__ __launch_bounds__(256) void k_scanC(const int* __restrict__ incl,
                                               const int* __restrict__ deg,
                                               const int* __restrict__ boff,
                                               int* __restrict__ rp) {
  int i = blockIdx.x * 256 + threadIdx.x;
  if (i < NN) rp[i] = incl[i] - deg[i] + boff[i >> 10];
  if (i == 0) rp[NN] = NE;
}

// ---------------- CSR bucket fill ----------------
__global__ __launch_bounds__(256) void k_fill(const int* __restrict__ src,
                                              const int* __restrict__ dst,
                                              const int* __restrict__ rp,
                                              int* __restrict__ fill,
                                              int* __restrict__ colsrc) {
  int e = blockIdx.x * 256 + threadIdx.x;
  if (e < NE) {
    int d = dst[e];
    int pos = rp[d] + atomicAdd(&fill[d], 1);
    colsrc[pos] = src[e];
  }
}

// ---- APPNP iteration: out = 0.8*ni*sum(h_scaled[s]) + 0.2*x0 ; opt *no on write
template <bool SCALE_OUT>
__global__ __launch_bounds__(256) void k_appnp(const __half2* __restrict__ h,
                                               const __half2* __restrict__ x0,
                                               const float* __restrict__ no,
                                               const float* __restrict__ ni,
                                               const int* __restrict__ rp,
                                               const int* __restrict__ cs,
                                               __half2* __restrict__ outp) {
  int w = (blockIdx.x * 256 + threadIdx.x) >> 6;
  int lane = threadIdx.x & 63;
  if (w >= NN) return;
  int beg = rp[w], end = rp[w + 1], cnt = end - beg;
  float ax = 0.f, ay = 0.f;
  for (int base = 0; base < cnt; base += 64) {
    int e = beg + base + lane;
    int cv = (e < end) ? cs[e] : 0;
    int m = cnt - base; if (m > 64) m = 64;
    for (int j = 0; j < m; ++j) {
      int s = __builtin_amdgcn_readlane(cv, j);
      float2 f = __half22float2(h[s * 64 + lane]);
      ax += f.x; ay += f.y;
    }
  }
  float wi = 0.8f * ni[w];
  float2 xv = __half22float2(x0[w * 64 + lane]);
  float rx = wi * ax + 0.2f * xv.x;
  float ry = wi * ay + 0.2f * xv.y;
  if (SCALE_OUT) { float sc = no[w]; rx *= sc; ry *= sc; }
  outp[w * 64 + lane] = __floats2half2_rn(rx, ry);
}

// ---------------- single-source neighbor sum ----------------
__global__ __launch_bounds__(256) void k_gather1(const __half2* __restrict__ h,
                                                 const int* __restrict__ rp,
                                                 const int* __restrict__ cs,
                                                 __half2* __restrict__ outp) {
  int w = (blockIdx.x * 256 + threadIdx.x) >> 6;
  int lane = threadIdx.x & 63;
  if (w >= NN) return;
  int beg = rp[w], end = rp[w + 1], cnt = end - beg;
  float ax = 0.f, ay = 0.f;
  for (int base = 0; base < cnt; base += 64) {
    int e = beg + base + lane;
    int cv = (e < end) ? cs[e] : 0;
    int m = cnt - base; if (m > 64) m = 64;
    for (int j = 0; j < m; ++j) {
      int s = __builtin_amdgcn_readlane(cv, j);
      float2 f = __half22float2(h[s * 64 + lane]);
      ax += f.x; ay += f.y;
    }
  }
  outp[w * 64 + lane] = __floats2half2_rn(ax, ay);
}

// ---------------- dual-source neighbor sum ----------------
__global__ __launch_bounds__(256) void k_gather2(const __half2* __restrict__ hx,
                                                 const __half2* __restrict__ hy,
                                                 const int* __restrict__ rp,
                                                 const int* __restrict__ cs,
                                                 __half2* __restrict__ ox,
                                                 __half2* __restrict__ oy) {
  int w = (blockIdx.x * 256 + threadIdx.x) >> 6;
  int lane = threadIdx.x & 63;
  if (w >= NN) return;
  int beg = rp[w], end = rp[w + 1], cnt = end - beg;
  float ax = 0.f, ay = 0.f, bx = 0.f, by = 0.f;
  for (int base = 0; base < cnt; base += 64) {
    int e = beg + base + lane;
    int cv = (e < end) ? cs[e] : 0;
    int m = cnt - base; if (m > 64) m = 64;
    for (int j = 0; j < m; ++j) {
      int s = __builtin_amdgcn_readlane(cv, j);
      float2 f = __half22float2(hx[s * 64 + lane]);
      float2 g = __half22float2(hy[s * 64 + lane]);
      ax += f.x; ay += f.y;
      bx += g.x; by += g.y;
    }
  }
  ox[w * 64 + lane] = __floats2half2_rn(ax, ay);
  oy[w * 64 + lane] = __floats2half2_rn(bx, by);
}

// ---- GIN GEMM: out = ((1+eps)*p + a) @ W + b ; fp16 A-inputs, f32 acc ----
// Inner loop: A tile stored k-major (Aw[k][row], pad 68), W col-swizzled
// (+4 floats per 32) -> 3x ds_read_b128 per 32 FMAs, broadcast-friendly.
template <int KTOT, bool MISH>
__global__ __launch_bounds__(256) void k_gemm(const __half2* __restrict__ p0,
                                              const __half2* __restrict__ a0,
                                              const __half2* __restrict__ p1,
                                              const __half2* __restrict__ a1,
                                              const float* __restrict__ Wg,
                                              const float* __restrict__ bias,
                                              const float* __restrict__ epsp,
                                              float* __restrict__ outf,
                                              __half2* __restrict__ outh) {
  __shared__ __align__(16) float Aw[32 * 68];    // [k][row], row pad 64->68
  __shared__ __align__(16) float Wl[32 * 144];   // [k][col swizzled 128->144]
  const int tid = threadIdx.x;
  const int rowBase = blockIdx.x * 64;
  const float e1 = 1.0f + epsp[0];
  float acc[4][8];
  #pragma unroll
  for (int i = 0; i < 4; ++i)
    #pragma unroll
    for (int j = 0; j < 8; ++j) acc[i][j] = 0.f;
  const int ty = tid >> 4, tx = tid & 15;
  const int wofs = tx * 8 + (tx >> 2) * 4;  // swizzled col base

  for (int kc = 0; kc < KTOT; kc += 32) {
    const __half2* P;
    const __half2* A;
    int kkb;
    if (KTOT == 256 && kc >= 128) { P = p1; A = a1; kkb = kc - 128; }
    else { P = p0; A = a0; kkb = kc; }
    // stage A: 64 rows x 32 k, 4 halves (8B) per element
    #pragma unroll
    for (int it = 0; it < 2; ++it) {
      int idx = tid + it * 256;       // [0,512)
      int q = idx & 7, r = idx >> 3;  // k_local = q*4
      int grow = rowBase + r;
      float zz[4];
      if (grow < NN) {
        int fi = grow * 32 + (kkb >> 2) + q;  // float2 index (4 halves)
        F2H up, ua;
        up.f = reinterpret_cast<const float2*>(P)[fi];
        ua.f = reinterpret_cast<const float2*>(A)[fi];
        float2 p01 = __half22float2(up.h[0]), p23 = __half22float2(up.h[1]);
        float2 a01 = __half22float2(ua.h[0]), a23 = __half22float2(ua.h[1]);
        zz[0] = e1 * p01.x + a01.x;
        zz[1] = e1 * p01.y + a01.y;
        zz[2] = e1 * p23.x + a23.x;
        zz[3] = e1 * p23.y + a23.y;
      } else {
        zz[0] = zz[1] = zz[2] = zz[3] = 0.f;
      }
      #pragma unroll
      for (int m = 0; m < 4; ++m) Aw[(q * 4 + m) * 68 + r] = zz[m];
    }
    // stage W: 32 x 128 f32, col-swizzled
    #pragma unroll
    for (int it = 0; it < 4; ++it) {
      int idx = tid + it * 256;  // [0,1024) float4s
      int k = idx >> 5, c4 = (idx & 31) * 4;
      float4 wv4 = reinterpret_cast<const float4*>(Wg + (size_t)(kc + k) * DD)[idx & 31];
      *reinterpret_cast<float4*>(&Wl[k * 144 + c4 + (c4 >> 5) * 4]) = wv4;
    }
    __syncthreads();
    #pragma unroll 8
    for (int k = 0; k < 32; ++k) {
      float4 av = *reinterpret_cast<const float4*>(&Aw[k * 68 + ty * 4]);
      float4 w0 = *reinterpret_cast<const float4*>(&Wl[k * 144 + wofs]);
      float4 w1 = *reinterpret_cast<const float4*>(&Wl[k * 144 + wofs + 4]);
      float a4[4] = {av.x, av.y, av.z, av.w};
      float w8[8] = {w0.x, w0.y, w0.z, w0.w, w1.x, w1.y, w1.z, w1.w};
      #pragma unroll
      for (int i = 0; i < 4; ++i)
        #pragma unroll
        for (int j = 0; j < 8; ++j) acc[i][j] += a4[i] * w8[j];
    }
    __syncthreads();
  }
  #pragma unroll
  for (int i = 0; i < 4; ++i) {
    int grow = rowBase + ty * 4 + i;
    if (grow < NN) {
      float v[8];
      #pragma unroll
      for (int j = 0; j < 8; ++j) {
        v[j] = acc[i][j] + bias[tx * 8 + j];
        if (MISH) {
          float sp = (v[j] > 20.f) ? v[j] : log1pf(expf(v[j]));
          v[j] = v[j] * tanhf(sp);
        }
      }
      if (MISH) {
        float4 o0 = {v[0], v[1], v[2], v[3]};
        float4 o1 = {v[4], v[5], v[6], v[7]};
        float* op = outf + (size_t)grow * DD + tx * 8;
        *reinterpret_cast<float4*>(op) = o0;
        *reinterpret_cast<float4*>(op + 4) = o1;
      } else {
        F2H o0, o1;
        o0.h[0] = __floats2half2_rn(v[0], v[1]);
        o0.h[1] = __floats2half2_rn(v[2], v[3]);
        o1.h[0] = __floats2half2_rn(v[4], v[5]);
        o1.h[1] = __floats2half2_rn(v[6], v[7]);
        float2* op = reinterpret_cast<float2*>(outh + (size_t)grow * 64 + tx * 4);
        op[0] = o0.f;
        op[1] = o1.f;
      }
    }
  }
}

extern "C" void kernel_launch(void* const* d_in, const int* in_sizes, int n_in,
                              void* d_out, int out_size, void* d_ws, size_t ws_size,
                              hipStream_t stream) {
  const float* x = (const float*)d_in[0];
  const int* src = (const int*)d_in[1];
  const int* dst = (const int*)d_in[2];
  const float* W1 = (const float*)d_in[3];
  const float* b1 = (const float*)d_in[4];
  const float* W2 = (const float*)d_in[5];
  const float* b2 = (const float*)d_in[6];
  const float* eps1 = (const float*)d_in[7];
  const float* eps2 = (const float*)d_in[8];
  float* out = (float*)d_out;

  char* ws = (char*)d_ws;
  size_t off = 0;
  auto alloc = [&](size_t bytes) -> void* {
    void* p = ws + off;
    off += (bytes + 255) & ~(size_t)255;
    return p;
  };
  const size_t ND = (size_t)NN * DD;
  __half2* x0h = (__half2*)alloc(ND * 2);  // tanh(x)
  __half2* x0n = (__half2*)alloc(ND * 2);  // tanh(x)*no ; later agg(x0)
  __half2* hA = (__half2*)alloc(ND * 2);
  __half2* hB = (__half2*)alloc(ND * 2);
  __half2* g1h = (__half2*)alloc(ND * 2);
  int* cnt_o = (int*)alloc(NN * 4);
  int* cnt_i = (int*)alloc(NN * 4);
  float* nrm_o = (float*)alloc(NN * 4);
  float* nrm_i = (float*)alloc(NN * 4);
  int* incl = (int*)alloc(NN * 4);
  int* bsum = (int*)alloc(64 * 4);
  int* boff = (int*)alloc(64 * 4);
  int* rp = (int*)alloc((NN + 1) * 4);
  int* fillc = (int*)alloc(NN * 4);
  int* colsrc = (int*)alloc(NE * 4);

  hipMemsetAsync(cnt_o, 0, NN * 4, stream);
  hipMemsetAsync(cnt_i, 0, NN * 4, stream);
  hipMemsetAsync(fillc, 0, NN * 4, stream);

  const int EB = (NE + 255) / 256;
  k_deg<<<EB, 256, 0, stream>>>(src, dst, cnt_o, cnt_i);
  k_norm<<<(NN + 255) / 256, 256, 0, stream>>>(cnt_o, cnt_i, nrm_o, nrm_i);

  const int SB = (NN + 1023) / 1024;  // 49
  k_scanA<<<SB, 1024, 0, stream>>>(cnt_i, incl, bsum);
  k_scanB<<<1, 64, 0, stream>>>(bsum, boff, SB);
  k_scanC<<<(NN + 255) / 256, 256, 0, stream>>>(incl, cnt_i, boff, rp);
  k_fill<<<EB, 256, 0, stream>>>(src, dst, rp, fillc, colsrc);

  k_tanh<<<(NN * DD / 4 + 255) / 256, 256, 0, stream>>>(x, nrm_o, x0h, x0n);

  const int GB = (NN * 64 + 255) / 256;  // wave per node
  // APPNP x5 (sources pre-scaled by no): x0n -> hA -> hB -> hA -> hB -> hA(unscaled)
  k_appnp<true><<<GB, 256, 0, stream>>>(x0n, x0h, nrm_o, nrm_i, rp, colsrc, hA);
  k_appnp<true><<<GB, 256, 0, stream>>>(hA, x0h, nrm_o, nrm_i, rp, colsrc, hB);
  k_appnp<true><<<GB, 256, 0, stream>>>(hB, x0h, nrm_o, nrm_i, rp, colsrc, hA);
  k_appnp<true><<<GB, 256, 0, stream>>>(hA, x0h, nrm_o, nrm_i, rp, colsrc, hB);
  k_appnp<false><<<GB, 256, 0, stream>>>(hB, x0h, nrm_o, nrm_i, rp, colsrc, hA);

  // agg(h5) -> hB ; agg(x0) -> x0n (x0n's scaled content no longer needed)
  k_gather2<<<GB, 256, 0, stream>>>(hA, x0h, rp, colsrc, hB, x0n);

  const int MB = (NN + 63) / 64;
  // GIN1: g1 = ((1+eps1)*h5 + agg_h5) @ W1 + b1  -> fp16
  k_gemm<128, false><<<MB, 256, 0, stream>>>(hA, hB, nullptr, nullptr, W1, b1, eps1,
                                             nullptr, g1h);
  // agg(g1) -> hA
  k_gather1<<<GB, 256, 0, stream>>>(g1h, rp, colsrc, hA);
  // GIN2: out = mish([ (1+e2)*g1 + agg_g1 | (1+e2)*x0 + agg_x0 ] @ W2 + b2)
  k_gemm<256, true><<<MB, 256, 0, stream>>>(g1h, hA, x0h, x0n, W2, b2, eps2,
                                            out, nullptr);
}

// Round 3
// 455.754 us; speedup vs baseline: 1.7377x; 1.1939x over previous
//
#include <hip/hip_runtime.h>
#include <hip/hip_fp16.h>
#include <math.h>

#define NN 50000
#define NE 600000
#define DD 128

union F2H { float2 f; __half2 h[2]; };

// ---------------- tanh + dual fp16 write (plain and *norm_o) ----------------
__global__ __launch_bounds__(256) void k_tanh(const float* __restrict__ x,
                                              const float* __restrict__ no,
                                              __half2* __restrict__ x0h,
                                              __half2* __restrict__ x0n) {
  int i = blockIdx.x * 256 + threadIdx.x;
  if (i >= NN * DD / 4) return;
  float4 v = reinterpret_cast<const float4*>(x)[i];
  float t0 = tanhf(v.x), t1 = tanhf(v.y), t2 = tanhf(v.z), t3 = tanhf(v.w);
  float s = no[i >> 5];  // 32 float4 per node row
  F2H a, b;
  a.h[0] = __floats2half2_rn(t0, t1);
  a.h[1] = __floats2half2_rn(t2, t3);
  b.h[0] = __floats2half2_rn(t0 * s, t1 * s);
  b.h[1] = __floats2half2_rn(t2 * s, t3 * s);
  reinterpret_cast<float2*>(x0h)[i] = a.f;
  reinterpret_cast<float2*>(x0n)[i] = b.f;
}

// ---------------- degree count ----------------
__global__ __launch_bounds__(256) void k_deg(const int* __restrict__ src,
                                             const int* __restrict__ dst,
                                             int* __restrict__ co,
                                             int* __restrict__ ci) {
  int e = blockIdx.x * 256 + threadIdx.x;
  if (e < NE) {
    atomicAdd(&co[src[e]], 1);
    atomicAdd(&ci[dst[e]], 1);
  }
}

__global__ __launch_bounds__(256) void k_norm(const int* __restrict__ co,
                                              const int* __restrict__ ci,
                                              float* __restrict__ no,
                                              float* __restrict__ ni) {
  int i = blockIdx.x * 256 + threadIdx.x;
  if (i < NN) {
    no[i] = rsqrtf((float)max(co[i], 1));
    ni[i] = rsqrtf((float)max(ci[i], 1));
  }
}

// ---------------- exclusive scan of in-degrees ----------------
__global__ __launch_bounds__(1024) void k_scanA(const int* __restrict__ deg,
                                                int* __restrict__ incl,
                                                int* __restrict__ bsum) {
  int tid = threadIdx.x;
  int gid = blockIdx.x * 1024 + tid;
  int v = (gid < NN) ? deg[gid] : 0;
  int lane = tid & 63;
  #pragma unroll
  for (int o = 1; o < 64; o <<= 1) {
    int n = __shfl_up(v, o);
    if (lane >= o) v += n;
  }
  __shared__ int ws[16];
  int wid = tid >> 6;
  if (lane == 63) ws[wid] = v;
  __syncthreads();
  if (tid < 16) {
    int s = ws[tid];
    #pragma unroll
    for (int o = 1; o < 16; o <<= 1) {
      int n = __shfl_up(s, o);
      if (tid >= o) s += n;
    }
    ws[tid] = s;
  }
  __syncthreads();
  if (wid > 0) v += ws[wid - 1];
  if (gid < NN) incl[gid] = v;
  if (tid == 1023) bsum[blockIdx.x] = v;
}

__global__ __launch_bounds__(64) void k_scanB(const int* __restrict__ bsum,
                                              int* __restrict__ boff, int nb) {
  int t = threadIdx.x;
  int v = (t < nb) ? bsum[t] : 0;
  int orig = v;
  #pragma unroll
  for (int o = 1; o < 64; o <<= 1) {
    int n = __shfl_up(v, o);
    if (t >= o) v += n;
  }
  if (t < nb) boff[t] = v - orig;  // exclusive
}

__global__ __launch_bounds__(256) void k_scanC(const int* __restrict__ incl,
                                               const int* __restrict__ deg,
                                               const int* __restrict__ boff,
                                               int* __restrict__ rp) {
  int i = blockIdx.x * 256 + threadIdx.x;
  if (i < NN) rp[i] = incl[i] - deg[i] + boff[i >> 10];
  if (i == 0) rp[NN] = NE;
}

// ---------------- CSR bucket fill ----------------
__global__ __launch_bounds__(256) void k_fill(const int* __restrict__ src,
                                              const int* __restrict__ dst,
                                              const int* __restrict__ rp,
                                              int* __restrict__ fill,
                                              int* __restrict__ colsrc) {
  int e = blockIdx.x * 256 + threadIdx.x;
  if (e < NE) {
    int d = dst[e];
    int pos = rp[d] + atomicAdd(&fill[d], 1);
    colsrc[pos] = src[e];
  }
}

// ---- APPNP iteration: out = 0.8*ni*sum(h_scaled[s]) + 0.2*x0 ; opt *no on write
// Edge loop unrolled x4: 4 independent loads in flight per iteration.
template <bool SCALE_OUT>
__global__ __launch_bounds__(256) void k_appnp(const __half2* __restrict__ h,
                                               const __half2* __restrict__ x0,
                                               const float* __restrict__ no,
                                               const float* __restrict__ ni,
                                               const int* __restrict__ rp,
                                               const int* __restrict__ cs,
                                               __half2* __restrict__ outp) {
  int w = (blockIdx.x * 256 + threadIdx.x) >> 6;
  int lane = threadIdx.x & 63;
  if (w >= NN) return;
  const __half2* hl = h + lane;
  int beg = rp[w], end = rp[w + 1], cnt = end - beg;
  float ax = 0.f, ay = 0.f, bx = 0.f, by = 0.f;
  for (int base = 0; base < cnt; base += 64) {
    int e = beg + base + lane;
    int cv = (e < end) ? cs[e] : 0;
    int m = cnt - base; if (m > 64) m = 64;
    int j = 0;
    for (; j + 4 <= m; j += 4) {
      int s0 = __builtin_amdgcn_readlane(cv, j);
      int s1 = __builtin_amdgcn_readlane(cv, j + 1);
      int s2 = __builtin_amdgcn_readlane(cv, j + 2);
      int s3 = __builtin_amdgcn_readlane(cv, j + 3);
      float2 f0 = __half22float2(hl[s0 * 64]);
      float2 f1 = __half22float2(hl[s1 * 64]);
      float2 f2 = __half22float2(hl[s2 * 64]);
      float2 f3 = __half22float2(hl[s3 * 64]);
      ax += f0.x; ay += f0.y;
      bx += f1.x; by += f1.y;
      ax += f2.x; ay += f2.y;
      bx += f3.x; by += f3.y;
    }
    for (; j < m; ++j) {
      int s = __builtin_amdgcn_readlane(cv, j);
      float2 f = __half22float2(hl[s * 64]);
      ax += f.x; ay += f.y;
    }
  }
  ax += bx; ay += by;
  float wi = 0.8f * ni[w];
  float2 xv = __half22float2(x0[w * 64 + lane]);
  float rx = wi * ax + 0.2f * xv.x;
  float ry = wi * ay + 0.2f * xv.y;
  if (SCALE_OUT) { float sc = no[w]; rx *= sc; ry *= sc; }
  outp[w * 64 + lane] = __floats2half2_rn(rx, ry);
}

// ---------------- single-source neighbor sum (unrolled x4) ----------------
__global__ __launch_bounds__(256) void k_gather1(const __half2* __restrict__ h,
                                                 const int* __restrict__ rp,
                                                 const int* __restrict__ cs,
                                                 __half2* __restrict__ outp) {
  int w = (blockIdx.x * 256 + threadIdx.x) >> 6;
  int lane = threadIdx.x & 63;
  if (w >= NN) return;
  const __half2* hl = h + lane;
  int beg = rp[w], end = rp[w + 1], cnt = end - beg;
  float ax = 0.f, ay = 0.f, bx = 0.f, by = 0.f;
  for (int base = 0; base < cnt; base += 64) {
    int e = beg + base + lane;
    int cv = (e < end) ? cs[e] : 0;
    int m = cnt - base; if (m > 64) m = 64;
    int j = 0;
    for (; j + 4 <= m; j += 4) {
      int s0 = __builtin_amdgcn_readlane(cv, j);
      int s1 = __builtin_amdgcn_readlane(cv, j + 1);
      int s2 = __builtin_amdgcn_readlane(cv, j + 2);
      int s3 = __builtin_amdgcn_readlane(cv, j + 3);
      float2 f0 = __half22float2(hl[s0 * 64]);
      float2 f1 = __half22float2(hl[s1 * 64]);
      float2 f2 = __half22float2(hl[s2 * 64]);
      float2 f3 = __half22float2(hl[s3 * 64]);
      ax += f0.x; ay += f0.y;
      bx += f1.x; by += f1.y;
      ax += f2.x; ay += f2.y;
      bx += f3.x; by += f3.y;
    }
    for (; j < m; ++j) {
      int s = __builtin_amdgcn_readlane(cv, j);
      float2 f = __half22float2(hl[s * 64]);
      ax += f.x; ay += f.y;
    }
  }
  ax += bx; ay += by;
  outp[w * 64 + lane] = __floats2half2_rn(ax, ay);
}

// ---------------- dual-source neighbor sum (unrolled x2 => 4 loads) ----------
__global__ __launch_bounds__(256) void k_gather2(const __half2* __restrict__ hx,
                                                 const __half2* __restrict__ hy,
                                                 const int* __restrict__ rp,
                                                 const int* __restrict__ cs,
                                                 __half2* __restrict__ ox,
                                                 __half2* __restrict__ oy) {
  int w = (blockIdx.x * 256 + threadIdx.x) >> 6;
  int lane = threadIdx.x & 63;
  if (w >= NN) return;
  const __half2* hxl = hx + lane;
  const __half2* hyl = hy + lane;
  int beg = rp[w], end = rp[w + 1], cnt = end - beg;
  float ax = 0.f, ay = 0.f, bx = 0.f, by = 0.f;
  float cx = 0.f, cy = 0.f, dx = 0.f, dy = 0.f;
  for (int base = 0; base < cnt; base += 64) {
    int e = beg + base + lane;
    int cv = (e < end) ? cs[e] : 0;
    int m = cnt - base; if (m > 64) m = 64;
    int j = 0;
    for (; j + 2 <= m; j += 2) {
      int s0 = __builtin_amdgcn_readlane(cv, j);
      int s1 = __builtin_amdgcn_readlane(cv, j + 1);
      float2 f0 = __half22float2(hxl[s0 * 64]);
      float2 g0 = __half22float2(hyl[s0 * 64]);
      float2 f1 = __half22float2(hxl[s1 * 64]);
      float2 g1 = __half22float2(hyl[s1 * 64]);
      ax += f0.x; ay += f0.y; bx += g0.x; by += g0.y;
      cx += f1.x; cy += f1.y; dx += g1.x; dy += g1.y;
    }
    for (; j < m; ++j) {
      int s = __builtin_amdgcn_readlane(cv, j);
      float2 f = __half22float2(hxl[s * 64]);
      float2 g = __half22float2(hyl[s * 64]);
      ax += f.x; ay += f.y; bx += g.x; by += g.y;
    }
  }
  ax += cx; ay += cy; bx += dx; by += dy;
  ox[w * 64 + lane] = __floats2half2_rn(ax, ay);
  oy[w * 64 + lane] = __floats2half2_rn(bx, by);
}

// ---- GIN GEMM: out = ((1+eps)*p + a) @ W + b ; 128x128 tile, 8x8/thread ----
// A staged k-major f32 (stride 132, conflict-free task map), W f32 col-swizzled.
#define KSA 132
#define KSW 144
template <int KTOT, bool MISH>
__global__ __launch_bounds__(256) void k_gemm(const __half2* __restrict__ p0,
                                              const __half2* __restrict__ a0,
                                              const __half2* __restrict__ p1,
                                              const __half2* __restrict__ a1,
                                              const float* __restrict__ Wg,
                                              const float* __restrict__ bias,
                                              const float* __restrict__ epsp,
                                              float* __restrict__ outf,
                                              __half2* __restrict__ outh) {
  __shared__ __align__(16) float Aw[32 * KSA];   // [k][row 0..127]
  __shared__ __align__(16) float Wl[32 * KSW];   // [k][col swizzled]
  const int tid = threadIdx.x;
  const int rowBase = blockIdx.x * 128;
  const float e1 = 1.0f + epsp[0];
  float acc[8][8];
  #pragma unroll
  for (int i = 0; i < 8; ++i)
    #pragma unroll
    for (int j = 0; j < 8; ++j) acc[i][j] = 0.f;
  const int ty = tid >> 4, tx = tid & 15;
  const int wofs = tx * 8 + (tx >> 2) * 4;  // swizzled col base (2-way max)

  for (int kc = 0; kc < KTOT; kc += 32) {
    const __half2* P;
    const __half2* A;
    int kkb;
    if (KTOT == 256 && kc >= 128) { P = p1; A = a1; kkb = kc - 128; }
    else { P = p0; A = a0; kkb = kc; }
    // stage A: 128 rows x 32 k. Task idx: r = idx&127 (lane-consecutive rows
    // -> LDS store banks hit exactly 2x = free), q = idx>>7 (k-quad).
    #pragma unroll
    for (int it = 0; it < 4; ++it) {
      int idx = tid + it * 256;       // [0,1024)
      int r = idx & 127, q = idx >> 7;
      int grow = rowBase + r;
      float zz[4];
      if (grow < NN) {
        int fi = grow * 32 + (kkb >> 2) + q;  // float2 index (4 halves)
        F2H up, ua;
        up.f = reinterpret_cast<const float2*>(P)[fi];
        ua.f = reinterpret_cast<const float2*>(A)[fi];
        float2 p01 = __half22float2(up.h[0]), p23 = __half22float2(up.h[1]);
        float2 a01 = __half22float2(ua.h[0]), a23 = __half22float2(ua.h[1]);
        zz[0] = e1 * p01.x + a01.x;
        zz[1] = e1 * p01.y + a01.y;
        zz[2] = e1 * p23.x + a23.x;
        zz[3] = e1 * p23.y + a23.y;
      } else {
        zz[0] = zz[1] = zz[2] = zz[3] = 0.f;
      }
      #pragma unroll
      for (int m = 0; m < 4; ++m) Aw[(q * 4 + m) * KSA + r] = zz[m];
    }
    // stage W: 32 x 128 f32, col-swizzled
    #pragma unroll
    for (int it = 0; it < 4; ++it) {
      int idx = tid + it * 256;  // [0,1024) float4s
      int k = idx >> 5, c4 = (idx & 31) * 4;
      float4 wv4 = reinterpret_cast<const float4*>(Wg + (size_t)(kc + k) * DD)[idx & 31];
      *reinterpret_cast<float4*>(&Wl[k * KSW + c4 + (c4 >> 5) * 4]) = wv4;
    }
    __syncthreads();
    #pragma unroll 8
    for (int k = 0; k < 32; ++k) {
      float4 av0 = *reinterpret_cast<const float4*>(&Aw[k * KSA + ty * 8]);
      float4 av1 = *reinterpret_cast<const float4*>(&Aw[k * KSA + ty * 8 + 4]);
      float4 w0 = *reinterpret_cast<const float4*>(&Wl[k * KSW + wofs]);
      float4 w1 = *reinterpret_cast<const float4*>(&Wl[k * KSW + wofs + 4]);
      float a8[8] = {av0.x, av0.y, av0.z, av0.w, av1.x, av1.y, av1.z, av1.w};
      float w8[8] = {w0.x, w0.y, w0.z, w0.w, w1.x, w1.y, w1.z, w1.w};
      #pragma unroll
      for (int i = 0; i < 8; ++i)
        #pragma unroll
        for (int j = 0; j < 8; ++j) acc[i][j] += a8[i] * w8[j];
    }
    __syncthreads();
  }
  #pragma unroll
  for (int i = 0; i < 8; ++i) {
    int grow = rowBase + ty * 8 + i;
    if (grow < NN) {
      float v[8];
      #pragma unroll
      for (int j = 0; j < 8; ++j) {
        v[j] = acc[i][j] + bias[tx * 8 + j];
        if (MISH) {
          float sp = (v[j] > 20.f) ? v[j] : log1pf(expf(v[j]));
          v[j] = v[j] * tanhf(sp);
        }
      }
      if (MISH) {
        float4 o0 = {v[0], v[1], v[2], v[3]};
        float4 o1 = {v[4], v[5], v[6], v[7]};
        float* op = outf + (size_t)grow * DD + tx * 8;
        *reinterpret_cast<float4*>(op) = o0;
        *reinterpret_cast<float4*>(op + 4) = o1;
      } else {
        F2H o0, o1;
        o0.h[0] = __floats2half2_rn(v[0], v[1]);
        o0.h[1] = __floats2half2_rn(v[2], v[3]);
        o1.h[0] = __floats2half2_rn(v[4], v[5]);
        o1.h[1] = __floats2half2_rn(v[6], v[7]);
        float2* op = reinterpret_cast<float2*>(outh + (size_t)grow * 64 + tx * 4);
        op[0] = o0.f;
        op[1] = o1.f;
      }
    }
  }
}

extern "C" void kernel_launch(void* const* d_in, const int* in_sizes, int n_in,
                              void* d_out, int out_size, void* d_ws, size_t ws_size,
                              hipStream_t stream) {
  const float* x = (const float*)d_in[0];
  const int* src = (const int*)d_in[1];
  const int* dst = (const int*)d_in[2];
  const float* W1 = (const float*)d_in[3];
  const float* b1 = (const float*)d_in[4];
  const float* W2 = (const float*)d_in[5];
  const float* b2 = (const float*)d_in[6];
  const float* eps1 = (const float*)d_in[7];
  const float* eps2 = (const float*)d_in[8];
  float* out = (float*)d_out;

  char* ws = (char*)d_ws;
  size_t off = 0;
  auto alloc = [&](size_t bytes) -> void* {
    void* p = ws + off;
    off += (bytes + 255) & ~(size_t)255;
    return p;
  };
  const size_t ND = (size_t)NN * DD;
  __half2* x0h = (__half2*)alloc(ND * 2);  // tanh(x)
  __half2* x0n = (__half2*)alloc(ND * 2);  // tanh(x)*no ; later agg(x0)
  __half2* hA = (__half2*)alloc(ND * 2);
  __half2* hB = (__half2*)alloc(ND * 2);
  __half2* g1h = (__half2*)alloc(ND * 2);
  int* cnt_o = (int*)alloc(NN * 4);
  int* cnt_i = (int*)alloc(NN * 4);
  float* nrm_o = (float*)alloc(NN * 4);
  float* nrm_i = (float*)alloc(NN * 4);
  int* incl = (int*)alloc(NN * 4);
  int* bsum = (int*)alloc(64 * 4);
  int* boff = (int*)alloc(64 * 4);
  int* rp = (int*)alloc((NN + 1) * 4);
  int* fillc = (int*)alloc(NN * 4);
  int* colsrc = (int*)alloc(NE * 4);

  hipMemsetAsync(cnt_o, 0, NN * 4, stream);
  hipMemsetAsync(cnt_i, 0, NN * 4, stream);
  hipMemsetAsync(fillc, 0, NN * 4, stream);

  const int EB = (NE + 255) / 256;
  k_deg<<<EB, 256, 0, stream>>>(src, dst, cnt_o, cnt_i);
  k_norm<<<(NN + 255) / 256, 256, 0, stream>>>(cnt_o, cnt_i, nrm_o, nrm_i);

  const int SB = (NN + 1023) / 1024;  // 49
  k_scanA<<<SB, 1024, 0, stream>>>(cnt_i, incl, bsum);
  k_scanB<<<1, 64, 0, stream>>>(bsum, boff, SB);
  k_scanC<<<(NN + 255) / 256, 256, 0, stream>>>(incl, cnt_i, boff, rp);
  k_fill<<<EB, 256, 0, stream>>>(src, dst, rp, fillc, colsrc);

  k_tanh<<<(NN * DD / 4 + 255) / 256, 256, 0, stream>>>(x, nrm_o, x0h, x0n);

  const int GB = (NN * 64 + 255) / 256;  // wave per node
  // APPNP x5 (sources pre-scaled by no): x0n -> hA -> hB -> hA -> hB -> hA(unscaled)
  k_appnp<true><<<GB, 256, 0, stream>>>(x0n, x0h, nrm_o, nrm_i, rp, colsrc, hA);
  k_appnp<true><<<GB, 256, 0, stream>>>(hA, x0h, nrm_o, nrm_i, rp, colsrc, hB);
  k_appnp<true><<<GB, 256, 0, stream>>>(hB, x0h, nrm_o, nrm_i, rp, colsrc, hA);
  k_appnp<true><<<GB, 256, 0, stream>>>(hA, x0h, nrm_o, nrm_i, rp, colsrc, hB);
  k_appnp<false><<<GB, 256, 0, stream>>>(hB, x0h, nrm_o, nrm_i, rp, colsrc, hA);

  // agg(h5) -> hB ; agg(x0) -> x0n (x0n's scaled content no longer needed)
  k_gather2<<<GB, 256, 0, stream>>>(hA, x0h, rp, colsrc, hB, x0n);

  const int MB = (NN + 127) / 128;
  // GIN1: g1 = ((1+eps1)*h5 + agg_h5) @ W1 + b1  -> fp16
  k_gemm<128, false><<<MB, 256, 0, stream>>>(hA, hB, nullptr, nullptr, W1, b1, eps1,
                                             nullptr, g1h);
  // agg(g1) -> hA
  k_gather1<<<GB, 256, 0, stream>>>(g1h, rp, colsrc, hA);
  // GIN2: out = mish([ (1+e2)*g1 + agg_g1 | (1+e2)*x0 + agg_x0 ] @ W2 + b2)
  k_gemm<256, true><<<MB, 256, 0, stream>>>(g1h, hA, x0h, x0n, W2, b2, eps2,
                                            out, nullptr);
}

// Round 4
// 418.822 us; speedup vs baseline: 1.8909x; 1.0882x over previous
//
#include <hip/hip_runtime.h>
#include <hip/hip_fp16.h>
#include <math.h>

#define NN 50000
#define NE 600000

typedef _Float16 half8_t __attribute__((ext_vector_type(8)));
typedef float f32x16 __attribute__((ext_vector_type(16)));

union F2H { float2 f; __half2 h[2]; };

// ---------------- tanh + dual fp16 write (plain and *norm_o) ----------------
__global__ __launch_bounds__(256) void k_tanh(const float* __restrict__ x,
                                              const float* __restrict__ no,
                                              __half2* __restrict__ x0h,
                                              __half2* __restrict__ x0n) {
  int i = blockIdx.x * 256 + threadIdx.x;
  if (i >= NN * 32) return;
  float4 v = reinterpret_cast<const float4*>(x)[i];
  float t0 = tanhf(v.x), t1 = tanhf(v.y), t2 = tanhf(v.z), t3 = tanhf(v.w);
  float s = no[i >> 5];  // 32 float4 per node row
  F2H a, b;
  a.h[0] = __floats2half2_rn(t0, t1);
  a.h[1] = __floats2half2_rn(t2, t3);
  b.h[0] = __floats2half2_rn(t0 * s, t1 * s);
  b.h[1] = __floats2half2_rn(t2 * s, t3 * s);
  reinterpret_cast<float2*>(x0h)[i] = a.f;
  reinterpret_cast<float2*>(x0n)[i] = b.f;
}

// ---------------- W transpose + fp16 convert (runs once, tiny) ----------------
__global__ __launch_bounds__(256) void k_wt(const float* __restrict__ W1,
                                            const float* __restrict__ W2,
                                            _Float16* __restrict__ w1t,
                                            _Float16* __restrict__ w2t) {
  int i = blockIdx.x * 256 + threadIdx.x;
  if (i < 128 * 128) {
    int n = i >> 7, k = i & 127;
    w1t[i] = (_Float16)W1[k * 128 + n];
  } else {
    int j = i - 128 * 128;
    if (j < 128 * 256) {
      int n = j >> 8, k = j & 255;
      w2t[j] = (_Float16)W2[k * 128 + n];
    }
  }
}

// ---------------- degree count ----------------
__global__ __launch_bounds__(256) void k_deg(const int* __restrict__ src,
                                             const int* __restrict__ dst,
                                             int* __restrict__ co,
                                             int* __restrict__ ci) {
  int e = blockIdx.x * 256 + threadIdx.x;
  if (e < NE) {
    atomicAdd(&co[src[e]], 1);
    atomicAdd(&ci[dst[e]], 1);
  }
}

__global__ __launch_bounds__(256) void k_norm(const int* __restrict__ co,
                                              const int* __restrict__ ci,
                                              float* __restrict__ no,
                                              float* __restrict__ ni) {
  int i = blockIdx.x * 256 + threadIdx.x;
  if (i < NN) {
    no[i] = rsqrtf((float)max(co[i], 1));
    ni[i] = rsqrtf((float)max(ci[i], 1));
  }
}

// ---------------- exclusive scan of in-degrees ----------------
__global__ __launch_bounds__(1024) void k_scanA(const int* __restrict__ deg,
                                                int* __restrict__ incl,
                                                int* __restrict__ bsum) {
  int tid = threadIdx.x;
  int gid = blockIdx.x * 1024 + tid;
  int v = (gid < NN) ? deg[gid] : 0;
  int lane = tid & 63;
  #pragma unroll
  for (int o = 1; o < 64; o <<= 1) {
    int n = __shfl_up(v, o);
    if (lane >= o) v += n;
  }
  __shared__ int ws[16];
  int wid = tid >> 6;
  if (lane == 63) ws[wid] = v;
  __syncthreads();
  if (tid < 16) {
    int s = ws[tid];
    #pragma unroll
    for (int o = 1; o < 16; o <<= 1) {
      int n = __shfl_up(s, o);
      if (tid >= o) s += n;
    }
    ws[tid] = s;
  }
  __syncthreads();
  if (wid > 0) v += ws[wid - 1];
  if (gid < NN) incl[gid] = v;
  if (tid == 1023) bsum[blockIdx.x] = v;
}

__global__ __launch_bounds__(64) void k_scanB(const int* __restrict__ bsum,
                                              int* __restrict__ boff, int nb) {
  int t = threadIdx.x;
  int v = (t < nb) ? bsum[t] : 0;
  int orig = v;
  #pragma unroll
  for (int o = 1; o < 64; o <<= 1) {
    int n = __shfl_up(v, o);
    if (t >= o) v += n;
  }
  if (t < nb) boff[t] = v - orig;  // exclusive
}

__global__ __launch_bounds__(256) void k_scanC(const int* __restrict__ incl,
                                               const int* __restrict__ deg,
                                               const int* __restrict__ boff,
                                               int* __restrict__ rp) {
  int i = blockIdx.x * 256 + threadIdx.x;
  if (i < NN) rp[i] = incl[i] - deg[i] + boff[i >> 10];
  if (i == 0) rp[NN] = NE;
}

// ---------------- CSR bucket fill ----------------
__global__ __launch_bounds__(256) void k_fill(const int* __restrict__ src,
                                              const int* __restrict__ dst,
                                              const int* __restrict__ rp,
                                              int* __restrict__ fill,
                                              int* __restrict__ colsrc) {
  int e = blockIdx.x * 256 + threadIdx.x;
  if (e < NE) {
    int d = dst[e];
    int pos = rp[d] + atomicAdd(&fill[d], 1);
    colsrc[pos] = src[e];
  }
}

// ---- APPNP iteration: out = 0.8*ni*sum(h_scaled[s]) + 0.2*x0 ; opt *no on write
template <bool SCALE_OUT>
__global__ __launch_bounds__(256) void k_appnp(const __half2* __restrict__ h,
                                               const __half2* __restrict__ x0,
                                               const float* __restrict__ no,
                                               const float* __restrict__ ni,
                                               const int* __restrict__ rp,
                                               const int* __restrict__ cs,
                                               __half2* __restrict__ outp) {
  int w = (blockIdx.x * 256 + threadIdx.x) >> 6;
  int lane = threadIdx.x & 63;
  if (w >= NN) return;
  const __half2* hl = h + lane;
  int beg = rp[w], end = rp[w + 1], cnt = end - beg;
  float ax = 0.f, ay = 0.f, bx = 0.f, by = 0.f;
  for (int base = 0; base < cnt; base += 64) {
    int e = beg + base + lane;
    int cv = (e < end) ? cs[e] : 0;
    int m = cnt - base; if (m > 64) m = 64;
    int j = 0;
    for (; j + 4 <= m; j += 4) {
      int s0 = __builtin_amdgcn_readlane(cv, j);
      int s1 = __builtin_amdgcn_readlane(cv, j + 1);
      int s2 = __builtin_amdgcn_readlane(cv, j + 2);
      int s3 = __builtin_amdgcn_readlane(cv, j + 3);
      float2 f0 = __half22float2(hl[s0 * 64]);
      float2 f1 = __half22float2(hl[s1 * 64]);
      float2 f2 = __half22float2(hl[s2 * 64]);
      float2 f3 = __half22float2(hl[s3 * 64]);
      ax += f0.x; ay += f0.y;
      bx += f1.x; by += f1.y;
      ax += f2.x; ay += f2.y;
      bx += f3.x; by += f3.y;
    }
    for (; j < m; ++j) {
      int s = __builtin_amdgcn_readlane(cv, j);
      float2 f = __half22float2(hl[s * 64]);
      ax += f.x; ay += f.y;
    }
  }
  ax += bx; ay += by;
  float wi = 0.8f * ni[w];
  float2 xv = __half22float2(x0[w * 64 + lane]);
  float rx = wi * ax + 0.2f * xv.x;
  float ry = wi * ay + 0.2f * xv.y;
  if (SCALE_OUT) { float sc = no[w]; rx *= sc; ry *= sc; }
  outp[w * 64 + lane] = __floats2half2_rn(rx, ry);
}

// ---- first APPNP pass fused with agg(x0): dual gather over (x0*no, x0) ----
// hout = no * (0.8*ni*sum(x0n[s]) + 0.2*x0[w]) ; zout = (1+eps2)*x0[w] + sum(x0[s])
__global__ __launch_bounds__(256) void k_appnp_first(const __half2* __restrict__ xs,
                                                     const __half2* __restrict__ xp,
                                                     const float* __restrict__ epsp,
                                                     const float* __restrict__ no,
                                                     const float* __restrict__ ni,
                                                     const int* __restrict__ rp,
                                                     const int* __restrict__ cs,
                                                     __half2* __restrict__ hout,
                                                     __half2* __restrict__ zout) {
  int w = (blockIdx.x * 256 + threadIdx.x) >> 6;
  int lane = threadIdx.x & 63;
  if (w >= NN) return;
  const __half2* xsl = xs + lane;
  const __half2* xpl = xp + lane;
  int beg = rp[w], end = rp[w + 1], cnt = end - beg;
  float ax = 0.f, ay = 0.f, bx = 0.f, by = 0.f;
  float cx = 0.f, cy = 0.f, dx = 0.f, dy = 0.f;
  for (int base = 0; base < cnt; base += 64) {
    int e = beg + base + lane;
    int cv = (e < end) ? cs[e] : 0;
    int m = cnt - base; if (m > 64) m = 64;
    int j = 0;
    for (; j + 2 <= m; j += 2) {
      int s0 = __builtin_amdgcn_readlane(cv, j);
      int s1 = __builtin_amdgcn_readlane(cv, j + 1);
      float2 f0 = __half22float2(xsl[s0 * 64]);
      float2 g0 = __half22float2(xpl[s0 * 64]);
      float2 f1 = __half22float2(xsl[s1 * 64]);
      float2 g1 = __half22float2(xpl[s1 * 64]);
      ax += f0.x; ay += f0.y; bx += g0.x; by += g0.y;
      cx += f1.x; cy += f1.y; dx += g1.x; dy += g1.y;
    }
    for (; j < m; ++j) {
      int s = __builtin_amdgcn_readlane(cv, j);
      float2 f = __half22float2(xsl[s * 64]);
      float2 g = __half22float2(xpl[s * 64]);
      ax += f.x; ay += f.y; bx += g.x; by += g.y;
    }
  }
  ax += cx; ay += cy; bx += dx; by += dy;
  float2 xv = __half22float2(xp[w * 64 + lane]);
  float wi = 0.8f * ni[w];
  float sc = no[w];
  hout[w * 64 + lane] = __floats2half2_rn(sc * (wi * ax + 0.2f * xv.x),
                                          sc * (wi * ay + 0.2f * xv.y));
  float e2 = 1.0f + epsp[0];
  zout[w * 64 + lane] = __floats2half2_rn(e2 * xv.x + bx, e2 * xv.y + by);
}

// ---- gather + GIN affine: z = (1+eps)*h[w] + sum(h[s]) ----------------------
__global__ __launch_bounds__(256) void k_gather_z(const __half2* __restrict__ h,
                                                  const float* __restrict__ epsp,
                                                  const int* __restrict__ rp,
                                                  const int* __restrict__ cs,
                                                  __half2* __restrict__ outp) {
  int w = (blockIdx.x * 256 + threadIdx.x) >> 6;
  int lane = threadIdx.x & 63;
  if (w >= NN) return;
  const __half2* hl = h + lane;
  int beg = rp[w], end = rp[w + 1], cnt = end - beg;
  float ax = 0.f, ay = 0.f, bx = 0.f, by = 0.f;
  for (int base = 0; base < cnt; base += 64) {
    int e = beg + base + lane;
    int cv = (e < end) ? cs[e] : 0;
    int m = cnt - base; if (m > 64) m = 64;
    int j = 0;
    for (; j + 4 <= m; j += 4) {
      int s0 = __builtin_amdgcn_readlane(cv, j);
      int s1 = __builtin_amdgcn_readlane(cv, j + 1);
      int s2 = __builtin_amdgcn_readlane(cv, j + 2);
      int s3 = __builtin_amdgcn_readlane(cv, j + 3);
      float2 f0 = __half22float2(hl[s0 * 64]);
      float2 f1 = __half22float2(hl[s1 * 64]);
      float2 f2 = __half22float2(hl[s2 * 64]);
      float2 f3 = __half22float2(hl[s3 * 64]);
      ax += f0.x; ay += f0.y;
      bx += f1.x; by += f1.y;
      ax += f2.x; ay += f2.y;
      bx += f3.x; by += f3.y;
    }
    for (; j < m; ++j) {
      int s = __builtin_amdgcn_readlane(cv, j);
      float2 f = __half22float2(hl[s * 64]);
      ax += f.x; ay += f.y;
    }
  }
  ax += bx; ay += by;
  float e1 = 1.0f + epsp[0];
  float2 hv = __half22float2(h[w * 64 + lane]);
  outp[w * 64 + lane] = __floats2half2_rn(e1 * hv.x + ax, e1 * hv.y + ay);
}

// ---- MFMA GEMM: C = Z @ W + b, Z fp16 [M][KTOT] (two halves if KTOT=256),
// W given transposed fp16 [128 n][KTOT k]. One wave per 32-row tile.
// mfma_f32_32x32x16_f16: A lane l: row=l&31, k=8*(l>>5)+j. B lane l: col=l&31,
// k=8*(l>>5)+j. C/D: col=lane&31, row=(reg&3)+8*(reg>>2)+4*(lane>>5).
template <int KTOT, bool MISH>
__global__ __launch_bounds__(64) void k_mgemm(const _Float16* __restrict__ z0,
                                              const _Float16* __restrict__ z1,
                                              const _Float16* __restrict__ wt,
                                              const float* __restrict__ bias,
                                              float* __restrict__ outf,
                                              __half2* __restrict__ outh) {
  int lane = threadIdx.x;
  int row0 = blockIdx.x * 32;
  if (row0 >= NN) return;
  int r31 = lane & 31, g = lane >> 5;
  f32x16 acc[4];
  #pragma unroll
  for (int i = 0; i < 4; ++i) acc[i] = (f32x16)(0.0f);
  const size_t arow = (size_t)(row0 + r31) * 128;
  #pragma unroll 4
  for (int ks = 0; ks < KTOT / 16; ++ks) {
    const _Float16* zp = (KTOT == 256 && ks >= 8) ? z1 : z0;
    int kloc = (KTOT == 256 && ks >= 8) ? (ks - 8) * 16 : ks * 16;
    half8_t a = *reinterpret_cast<const half8_t*>(zp + arow + kloc + 8 * g);
    #pragma unroll
    for (int nb = 0; nb < 4; ++nb) {
      half8_t b = *reinterpret_cast<const half8_t*>(
          wt + (size_t)(nb * 32 + r31) * KTOT + ks * 16 + 8 * g);
      acc[nb] = __builtin_amdgcn_mfma_f32_32x32x16_f16(a, b, acc[nb], 0, 0, 0);
    }
  }
  #pragma unroll
  for (int nb = 0; nb < 4; ++nb) {
    float bv = bias[nb * 32 + r31];
    #pragma unroll
    for (int r = 0; r < 16; ++r) {
      int rl = (r & 3) + 8 * (r >> 2) + 4 * g;
      int grow = row0 + rl;
      if (grow < NN) {
        float v = acc[nb][r] + bv;
        if (MISH) {
          float sp = (v > 20.f) ? v : log1pf(expf(v));
          v = v * tanhf(sp);
          outf[(size_t)grow * 128 + nb * 32 + r31] = v;
        } else {
          float u = __shfl_xor(v, 1);
          if (!(lane & 1)) {
            outh[((size_t)grow * 128 + nb * 32 + r31) >> 1] = __floats2half2_rn(v, u);
          }
        }
      }
    }
  }
}

extern "C" void kernel_launch(void* const* d_in, const int* in_sizes, int n_in,
                              void* d_out, int out_size, void* d_ws, size_t ws_size,
                              hipStream_t stream) {
  const float* x = (const float*)d_in[0];
  const int* src = (const int*)d_in[1];
  const int* dst = (const int*)d_in[2];
  const float* W1 = (const float*)d_in[3];
  const float* b1 = (const float*)d_in[4];
  const float* W2 = (const float*)d_in[5];
  const float* b2 = (const float*)d_in[6];
  const float* eps1 = (const float*)d_in[7];
  const float* eps2 = (const float*)d_in[8];
  float* out = (float*)d_out;

  char* ws = (char*)d_ws;
  size_t off = 0;
  auto alloc = [&](size_t bytes) -> void* {
    void* p = ws + off;
    off += (bytes + 255) & ~(size_t)255;
    return p;
  };
  const size_t ND = (size_t)NN * 128;
  __half2* x0h = (__half2*)alloc(ND * 2);  // tanh(x)
  __half2* x0n = (__half2*)alloc(ND * 2);  // tanh(x)*no ; later z1 (GIN1 input)
  __half2* hA = (__half2*)alloc(ND * 2);
  __half2* hB = (__half2*)alloc(ND * 2);   // later zg (GIN2 first half)
  __half2* zx = (__half2*)alloc(ND * 2);   // (1+e2)*x0 + agg(x0)
  __half2* g1h = (__half2*)alloc(ND * 2);  // GIN1 output
  _Float16* w1t = (_Float16*)alloc(128 * 128 * 2);
  _Float16* w2t = (_Float16*)alloc(128 * 256 * 2);
  int* cnt_o = (int*)alloc(NN * 4);
  int* cnt_i = (int*)alloc(NN * 4);
  float* nrm_o = (float*)alloc(NN * 4);
  float* nrm_i = (float*)alloc(NN * 4);
  int* incl = (int*)alloc(NN * 4);
  int* bsum = (int*)alloc(64 * 4);
  int* boff = (int*)alloc(64 * 4);
  int* rp = (int*)alloc((NN + 1) * 4);
  int* fillc = (int*)alloc(NN * 4);
  int* colsrc = (int*)alloc(NE * 4);

  hipMemsetAsync(cnt_o, 0, NN * 4, stream);
  hipMemsetAsync(cnt_i, 0, NN * 4, stream);
  hipMemsetAsync(fillc, 0, NN * 4, stream);

  const int EB = (NE + 255) / 256;
  k_deg<<<EB, 256, 0, stream>>>(src, dst, cnt_o, cnt_i);
  k_norm<<<(NN + 255) / 256, 256, 0, stream>>>(cnt_o, cnt_i, nrm_o, nrm_i);

  const int SB = (NN + 1023) / 1024;  // 49
  k_scanA<<<SB, 1024, 0, stream>>>(cnt_i, incl, bsum);
  k_scanB<<<1, 64, 0, stream>>>(bsum, boff, SB);
  k_scanC<<<(NN + 255) / 256, 256, 0, stream>>>(incl, cnt_i, boff, rp);
  k_fill<<<EB, 256, 0, stream>>>(src, dst, rp, fillc, colsrc);

  k_tanh<<<(NN * 32 + 255) / 256, 256, 0, stream>>>(x, nrm_o, x0h, x0n);
  k_wt<<<192, 256, 0, stream>>>(W1, W2, w1t, w2t);

  const int GB = (NN * 64 + 255) / 256;  // wave per node
  // APPNP iter1 fused with agg(x0): -> hA (scaled), zx
  k_appnp_first<<<GB, 256, 0, stream>>>(x0n, x0h, eps2, nrm_o, nrm_i, rp, colsrc,
                                        hA, zx);
  // APPNP iters 2..5
  k_appnp<true><<<GB, 256, 0, stream>>>(hA, x0h, nrm_o, nrm_i, rp, colsrc, hB);
  k_appnp<true><<<GB, 256, 0, stream>>>(hB, x0h, nrm_o, nrm_i, rp, colsrc, hA);
  k_appnp<true><<<GB, 256, 0, stream>>>(hA, x0h, nrm_o, nrm_i, rp, colsrc, hB);
  k_appnp<false><<<GB, 256, 0, stream>>>(hB, x0h, nrm_o, nrm_i, rp, colsrc, hA);

  // z1 = (1+eps1)*h5 + agg(h5) -> x0n (scaled-x0 content is dead now)
  k_gather_z<<<GB, 256, 0, stream>>>(hA, eps1, rp, colsrc, x0n);

  const int TB = (NN + 31) / 32;  // 1563 one-wave tiles
  // GIN1: g1 = z1 @ W1 + b1 -> fp16
  k_mgemm<128, false><<<TB, 64, 0, stream>>>((const _Float16*)x0n, nullptr, w1t, b1,
                                             nullptr, g1h);
  // zg = (1+eps2)*g1 + agg(g1) -> hB
  k_gather_z<<<GB, 256, 0, stream>>>(g1h, eps2, rp, colsrc, hB);
  // GIN2: out = mish([zg | zx] @ W2 + b2)
  k_mgemm<256, true><<<TB, 64, 0, stream>>>((const _Float16*)hB, (const _Float16*)zx,
                                            w2t, b2, out, nullptr);
}

// Round 5
// 373.190 us; speedup vs baseline: 2.1222x; 1.1223x over previous
//
#include <hip/hip_runtime.h>
#include <hip/hip_fp16.h>
#include <math.h>

#define NN 50000
#define NE 600000
#define NT ((NN + 31) / 32)   // 1563 row-tiles of 32

typedef _Float16 half8_t __attribute__((ext_vector_type(8)));
typedef float f32x16 __attribute__((ext_vector_type(16)));

union F2H { float2 f; __half2 h[2]; };

// Packed fragment layout for MFMA (32x32x16_f16):
//   element (row r in tile t, feature k): ks=k>>4, g=(k&15)>>3, j=k&7
//   halves index = ((t*8 + ks)*64 + g*32 + r)*8 + j   (per 128-k buffer)
// A wave loads fragment ks as 64 lanes x 16B contiguous (1KB).

// ---------------- tanh + dual fp16 write (plain and *norm_o) ----------------
__global__ __launch_bounds__(256) void k_tanh(const float* __restrict__ x,
                                              const float* __restrict__ no,
                                              __half2* __restrict__ x0h,
                                              __half2* __restrict__ x0n) {
  int i = blockIdx.x * 256 + threadIdx.x;
  if (i >= NN * 32) return;
  float4 v = reinterpret_cast<const float4*>(x)[i];
  float t0 = tanhf(v.x), t1 = tanhf(v.y), t2 = tanhf(v.z), t3 = tanhf(v.w);
  float s = no[i >> 5];  // 32 float4 per node row
  F2H a, b;
  a.h[0] = __floats2half2_rn(t0, t1);
  a.h[1] = __floats2half2_rn(t2, t3);
  b.h[0] = __floats2half2_rn(t0 * s, t1 * s);
  b.h[1] = __floats2half2_rn(t2 * s, t3 * s);
  reinterpret_cast<float2*>(x0h)[i] = a.f;
  reinterpret_cast<float2*>(x0n)[i] = b.f;
}

// ------------- W transpose -> fragment-packed fp16 (runs once, tiny) --------
__global__ __launch_bounds__(256) void k_wt(const float* __restrict__ W1,
                                            const float* __restrict__ W2,
                                            _Float16* __restrict__ w1p,
                                            _Float16* __restrict__ w2p) {
  int i = blockIdx.x * 256 + threadIdx.x;
  if (i < 128 * 128) {
    int k = i >> 7, n = i & 127;
    int nb = n >> 5, r = n & 31, ks = k >> 4, g = (k & 15) >> 3, j = k & 7;
    w1p[(((ks << 2) + nb) * 64 + (g << 5) + r) * 8 + j] = (_Float16)W1[i];
  } else {
    int q = i - 128 * 128;
    if (q < 256 * 128) {
      int k = q >> 7, n = q & 127;
      int nb = n >> 5, r = n & 31, ks = k >> 4, g = (k & 15) >> 3, j = k & 7;
      w2p[(((ks << 2) + nb) * 64 + (g << 5) + r) * 8 + j] = (_Float16)W2[q];
    }
  }
}

// ---------------- degree count ----------------
__global__ __launch_bounds__(256) void k_deg(const int* __restrict__ src,
                                             const int* __restrict__ dst,
                                             int* __restrict__ co,
                                             int* __restrict__ ci) {
  int e = blockIdx.x * 256 + threadIdx.x;
  if (e < NE) {
    atomicAdd(&co[src[e]], 1);
    atomicAdd(&ci[dst[e]], 1);
  }
}

__global__ __launch_bounds__(256) void k_norm(const int* __restrict__ co,
                                              const int* __restrict__ ci,
                                              float* __restrict__ no,
                                              float* __restrict__ ni) {
  int i = blockIdx.x * 256 + threadIdx.x;
  if (i < NN) {
    no[i] = rsqrtf((float)max(co[i], 1));
    ni[i] = rsqrtf((float)max(ci[i], 1));
  }
}

// ---------------- exclusive scan of in-degrees ----------------
__global__ __launch_bounds__(1024) void k_scanA(const int* __restrict__ deg,
                                                int* __restrict__ incl,
                                                int* __restrict__ bsum) {
  int tid = threadIdx.x;
  int gid = blockIdx.x * 1024 + tid;
  int v = (gid < NN) ? deg[gid] : 0;
  int lane = tid & 63;
  #pragma unroll
  for (int o = 1; o < 64; o <<= 1) {
    int n = __shfl_up(v, o);
    if (lane >= o) v += n;
  }
  __shared__ int ws[16];
  int wid = tid >> 6;
  if (lane == 63) ws[wid] = v;
  __syncthreads();
  if (tid < 16) {
    int s = ws[tid];
    #pragma unroll
    for (int o = 1; o < 16; o <<= 1) {
      int n = __shfl_up(s, o);
      if (tid >= o) s += n;
    }
    ws[tid] = s;
  }
  __syncthreads();
  if (wid > 0) v += ws[wid - 1];
  if (gid < NN) incl[gid] = v;
  if (tid == 1023) bsum[blockIdx.x] = v;
}

__global__ __launch_bounds__(64) void k_scanB(const int* __restrict__ bsum,
                                              int* __restrict__ boff, int nb) {
  int t = threadIdx.x;
  int v = (t < nb) ? bsum[t] : 0;
  int orig = v;
  #pragma unroll
  for (int o = 1; o < 64; o <<= 1) {
    int n = __shfl_up(v, o);
    if (t >= o) v += n;
  }
  if (t < nb) boff[t] = v - orig;  // exclusive
}

__global__ __launch_bounds__(256) void k_scanC(const int* __restrict__ incl,
                                               const int* __restrict__ deg,
                                               const int* __restrict__ boff,
                                               int* __restrict__ rp) {
  int i = blockIdx.x * 256 + threadIdx.x;
  if (i < NN) rp[i] = incl[i] - deg[i] + boff[i >> 10];
  if (i == 0) rp[NN] = NE;
}

// ---------------- CSR bucket fill ----------------
__global__ __launch_bounds__(256) void k_fill(const int* __restrict__ src,
                                              const int* __restrict__ dst,
                                              const int* __restrict__ rp,
                                              int* __restrict__ fill,
                                              int* __restrict__ colsrc) {
  int e = blockIdx.x * 256 + threadIdx.x;
  if (e < NE) {
    int d = dst[e];
    int pos = rp[d] + atomicAdd(&fill[d], 1);
    colsrc[pos] = src[e];
  }
}

#define GATHER_LOOP(LOADEXPR)                                        \
  for (int base = 0; base < cnt; base += 64) {                      \
    int e = beg + base + lane;                                      \
    int cv = (e < end) ? cs[e] : 0;                                 \
    int m = cnt - base; if (m > 64) m = 64;                         \
    int j = 0;                                                      \
    for (; j + 8 <= m; j += 8) {                                    \
      _Pragma("unroll")                                             \
      for (int u = 0; u < 8; ++u) {                                 \
        int s = __builtin_amdgcn_readlane(cv, j + u);               \
        LOADEXPR;                                                   \
      }                                                             \
    }                                                               \
    for (; j < m; ++j) {                                            \
      int s = __builtin_amdgcn_readlane(cv, j);                     \
      LOADEXPR;                                                     \
    }                                                               \
  }

// ---- APPNP iteration: out = 0.8*ni*sum(h_scaled[s]) + 0.2*x0 ; opt *no ----
template <bool SCALE_OUT>
__global__ __launch_bounds__(256) void k_appnp(const __half2* __restrict__ h,
                                               const __half2* __restrict__ x0,
                                               const float* __restrict__ no,
                                               const float* __restrict__ ni,
                                               const int* __restrict__ rp,
                                               const int* __restrict__ cs,
                                               __half2* __restrict__ outp) {
  int w = (blockIdx.x * 256 + threadIdx.x) >> 6;
  int lane = threadIdx.x & 63;
  if (w >= NN) return;
  const __half2* hl = h + lane;
  int beg = rp[w], end = rp[w + 1], cnt = end - beg;
  float ax = 0.f, ay = 0.f;
  GATHER_LOOP({
    float2 f = __half22float2(hl[s * 64]);
    ax += f.x; ay += f.y;
  })
  float wi = 0.8f * ni[w];
  float2 xv = __half22float2(x0[w * 64 + lane]);
  float rx = wi * ax + 0.2f * xv.x;
  float ry = wi * ay + 0.2f * xv.y;
  if (SCALE_OUT) { float sc = no[w]; rx *= sc; ry *= sc; }
  outp[w * 64 + lane] = __floats2half2_rn(rx, ry);
}

// packed-store helper: thread (node w, lane) holds features (2*lane, 2*lane+1)
__device__ inline void store_packed(_Float16* __restrict__ zp, int w, int lane,
                                    float v0, float v1) {
  int t = w >> 5, r = w & 31;
  int ks = lane >> 3, g = (lane >> 2) & 1, j = (lane & 3) * 2;
  size_t addr = (((size_t)t * 8 + ks) * 64 + g * 32 + r) * 8 + j;
  *reinterpret_cast<__half2*>(zp + addr) = __floats2half2_rn(v0, v1);
}

// ---- first APPNP pass fused with agg(x0): dual gather over (x0*no, x0) ----
// hout = no*(0.8*ni*sum(x0n[s]) + 0.2*x0[w]) ; zout(packed) = (1+e2)*x0[w]+sum(x0[s])
__global__ __launch_bounds__(256) void k_appnp_first(const __half2* __restrict__ xs,
                                                     const __half2* __restrict__ xp,
                                                     const float* __restrict__ epsp,
                                                     const float* __restrict__ no,
                                                     const float* __restrict__ ni,
                                                     const int* __restrict__ rp,
                                                     const int* __restrict__ cs,
                                                     __half2* __restrict__ hout,
                                                     _Float16* __restrict__ zout) {
  int w = (blockIdx.x * 256 + threadIdx.x) >> 6;
  int lane = threadIdx.x & 63;
  if (w >= NN) return;
  const __half2* xsl = xs + lane;
  const __half2* xpl = xp + lane;
  int beg = rp[w], end = rp[w + 1], cnt = end - beg;
  float ax = 0.f, ay = 0.f, bx = 0.f, by = 0.f;
  GATHER_LOOP({
    float2 f = __half22float2(xsl[s * 64]);
    float2 g2 = __half22float2(xpl[s * 64]);
    ax += f.x; ay += f.y; bx += g2.x; by += g2.y;
  })
  float2 xv = __half22float2(xp[w * 64 + lane]);
  float wi = 0.8f * ni[w];
  float sc = no[w];
  hout[w * 64 + lane] = __floats2half2_rn(sc * (wi * ax + 0.2f * xv.x),
                                          sc * (wi * ay + 0.2f * xv.y));
  float e2 = 1.0f + epsp[0];
  store_packed(zout, w, lane, e2 * xv.x + bx, e2 * xv.y + by);
}

// ---- gather + GIN affine, packed out: z = (1+eps)*h[w] + sum(h[s]) ---------
__global__ __launch_bounds__(256) void k_gather_z(const __half2* __restrict__ h,
                                                  const float* __restrict__ epsp,
                                                  const int* __restrict__ rp,
                                                  const int* __restrict__ cs,
                                                  _Float16* __restrict__ zout) {
  int w = (blockIdx.x * 256 + threadIdx.x) >> 6;
  int lane = threadIdx.x & 63;
  if (w >= NN) return;
  const __half2* hl = h + lane;
  int beg = rp[w], end = rp[w + 1], cnt = end - beg;
  float ax = 0.f, ay = 0.f;
  GATHER_LOOP({
    float2 f = __half22float2(hl[s * 64]);
    ax += f.x; ay += f.y;
  })
  float e1 = 1.0f + epsp[0];
  float2 hv = __half22float2(h[w * 64 + lane]);
  store_packed(zout, w, lane, e1 * hv.x + ax, e1 * hv.y + ay);
}

// ---- MFMA GEMM on packed operands: C = Z @ W + b -------------------------
// z0/z1: fragment-packed 128-k buffers; wp: fragment-packed weights.
// All loads are 64-lane x 16B contiguous. One wave per 32-row tile.
template <int KTOT, bool MISH>
__global__ __launch_bounds__(64) void k_mgemm(const _Float16* __restrict__ z0,
                                              const _Float16* __restrict__ z1,
                                              const _Float16* __restrict__ wp,
                                              const float* __restrict__ bias,
                                              float* __restrict__ outf,
                                              __half2* __restrict__ outh) {
  int lane = threadIdx.x;
  int t = blockIdx.x;
  int row0 = t * 32;
  if (row0 >= NN) return;
  int r31 = lane & 31, g = lane >> 5;
  f32x16 acc[4];
  #pragma unroll
  for (int i = 0; i < 4; ++i) acc[i] = (f32x16)(0.0f);
  #pragma unroll 4
  for (int ks = 0; ks < KTOT / 16; ++ks) {
    const _Float16* zp = (KTOT == 256 && ks >= 8) ? z1 : z0;
    int kls = (KTOT == 256) ? (ks & 7) : ks;
    half8_t a = *reinterpret_cast<const half8_t*>(
        zp + (((size_t)t * 8 + kls) * 64 + lane) * 8);
    #pragma unroll
    for (int nb = 0; nb < 4; ++nb) {
      half8_t b = *reinterpret_cast<const half8_t*>(
          wp + (((size_t)ks * 4 + nb) * 64 + lane) * 8);
      acc[nb] = __builtin_amdgcn_mfma_f32_32x32x16_f16(a, b, acc[nb], 0, 0, 0);
    }
  }
  #pragma unroll
  for (int nb = 0; nb < 4; ++nb) {
    float bv = bias[nb * 32 + r31];
    #pragma unroll
    for (int r = 0; r < 16; ++r) {
      int rl = (r & 3) + 8 * (r >> 2) + 4 * g;
      int grow = row0 + rl;
      if (grow < NN) {
        float v = acc[nb][r] + bv;
        if (MISH) {
          // mish(v) = v*q/(q+2), q = E(E+2), E = e^v   (== v*tanh(softplus(v)))
          float E = __expf(v);
          float q = E * (E + 2.f);
          float mv = v * q / (q + 2.f);
          v = (v > 15.f) ? v : mv;
          outf[(size_t)grow * 128 + nb * 32 + r31] = v;
        } else {
          float u = __shfl_xor(v, 1);
          if (!(lane & 1)) {
            outh[((size_t)grow * 128 + nb * 32 + r31) >> 1] = __floats2half2_rn(v, u);
          }
        }
      }
    }
  }
}

extern "C" void kernel_launch(void* const* d_in, const int* in_sizes, int n_in,
                              void* d_out, int out_size, void* d_ws, size_t ws_size,
                              hipStream_t stream) {
  const float* x = (const float*)d_in[0];
  const int* src = (const int*)d_in[1];
  const int* dst = (const int*)d_in[2];
  const float* W1 = (const float*)d_in[3];
  const float* b1 = (const float*)d_in[4];
  const float* W2 = (const float*)d_in[5];
  const float* b2 = (const float*)d_in[6];
  const float* eps1 = (const float*)d_in[7];
  const float* eps2 = (const float*)d_in[8];
  float* out = (float*)d_out;

  char* ws = (char*)d_ws;
  size_t off = 0;
  auto alloc = [&](size_t bytes) -> void* {
    void* p = ws + off;
    off += (bytes + 255) & ~(size_t)255;
    return p;
  };
  const size_t NDP = (size_t)NT * 4096;  // padded (packed) halves per buffer
  __half2* x0h = (__half2*)alloc(NDP * 2);   // tanh(x), row-major
  __half2* x0n = (__half2*)alloc(NDP * 2);   // tanh(x)*no ; later z1 packed
  __half2* hA = (__half2*)alloc(NDP * 2);    // row-major h
  __half2* hB = (__half2*)alloc(NDP * 2);    // row-major h ; later zg packed
  __half2* zx = (__half2*)alloc(NDP * 2);    // packed (1+e2)*x0 + agg(x0)
  __half2* g1h = (__half2*)alloc(NDP * 2);   // GIN1 out, row-major
  _Float16* w1p = (_Float16*)alloc(128 * 128 * 2);
  _Float16* w2p = (_Float16*)alloc(256 * 128 * 2);
  int* cnt_o = (int*)alloc(NN * 4);
  int* cnt_i = (int*)alloc(NN * 4);
  float* nrm_o = (float*)alloc(NN * 4);
  float* nrm_i = (float*)alloc(NN * 4);
  int* incl = (int*)alloc(NN * 4);
  int* bsum = (int*)alloc(64 * 4);
  int* boff = (int*)alloc(64 * 4);
  int* rp = (int*)alloc((NN + 1) * 4);
  int* fillc = (int*)alloc(NN * 4);
  int* colsrc = (int*)alloc(NE * 4);

  hipMemsetAsync(cnt_o, 0, NN * 4, stream);
  hipMemsetAsync(cnt_i, 0, NN * 4, stream);
  hipMemsetAsync(fillc, 0, NN * 4, stream);

  const int EB = (NE + 255) / 256;
  k_deg<<<EB, 256, 0, stream>>>(src, dst, cnt_o, cnt_i);
  k_norm<<<(NN + 255) / 256, 256, 0, stream>>>(cnt_o, cnt_i, nrm_o, nrm_i);

  const int SB = (NN + 1023) / 1024;  // 49
  k_scanA<<<SB, 1024, 0, stream>>>(cnt_i, incl, bsum);
  k_scanB<<<1, 64, 0, stream>>>(bsum, boff, SB);
  k_scanC<<<(NN + 255) / 256, 256, 0, stream>>>(incl, cnt_i, boff, rp);
  k_fill<<<EB, 256, 0, stream>>>(src, dst, rp, fillc, colsrc);

  k_tanh<<<(NN * 32 + 255) / 256, 256, 0, stream>>>(x, nrm_o, x0h, x0n);
  k_wt<<<192, 256, 0, stream>>>(W1, W2, w1p, w2p);

  const int GB = (NN * 64 + 255) / 256;  // wave per node
  // APPNP iter1 fused with agg(x0): -> hA (row-major, scaled), zx (packed)
  k_appnp_first<<<GB, 256, 0, stream>>>(x0n, x0h, eps2, nrm_o, nrm_i, rp, colsrc,
                                        hA, (_Float16*)zx);
  // APPNP iters 2..5
  k_appnp<true><<<GB, 256, 0, stream>>>(hA, x0h, nrm_o, nrm_i, rp, colsrc, hB);
  k_appnp<true><<<GB, 256, 0, stream>>>(hB, x0h, nrm_o, nrm_i, rp, colsrc, hA);
  k_appnp<true><<<GB, 256, 0, stream>>>(hA, x0h, nrm_o, nrm_i, rp, colsrc, hB);
  k_appnp<false><<<GB, 256, 0, stream>>>(hB, x0h, nrm_o, nrm_i, rp, colsrc, hA);

  // z1(packed) = (1+eps1)*h5 + agg(h5) -> x0n (scaled-x0 content is dead now)
  k_gather_z<<<GB, 256, 0, stream>>>(hA, eps1, rp, colsrc, (_Float16*)x0n);

  // GIN1: g1 = z1 @ W1 + b1 -> fp16 row-major
  k_mgemm<128, false><<<NT, 64, 0, stream>>>((const _Float16*)x0n, nullptr, w1p, b1,
                                             nullptr, g1h);
  // zg(packed) = (1+eps2)*g1 + agg(g1) -> hB
  k_gather_z<<<GB, 256, 0, stream>>>(g1h, eps2, rp, colsrc, (_Float16*)hB);
  // GIN2: out = mish([zg | zx] @ W2 + b2)
  k_mgemm<256, true><<<NT, 64, 0, stream>>>((const _Float16*)hB, (const _Float16*)zx,
                                            w2p, b2, out, nullptr);
}